// Round 4
// baseline (186.578 us; speedup 1.0000x reference)
//
#include <hip/hip_runtime.h>

// LIF recurrence: u_t = decay*u_{t-1} + x_t - o_{t-1}*VTH ; o_t = (u_t - VTH > 0)
// x: [B=64, N=4096, T=100] f32, T contiguous (400 B per neuron row).
//
// R10: store-policy A/B. Evidence: every prior kernel's duration ==
// WRITE_SIZE / 1.6 TB/s (R6: 102.5MB/63.8us=1.61; R8: 217.8/138.4=1.57;
// R9: 102.5/65.0=1.58) across completely different schedules, occupancies
// (12%-32%) and read traffic (51-189 MB). Write-path-bound, schedule-
// independent. All pinned kernels used __builtin_nontemporal_store; FETCH
// being exactly 50% of input each dispatch shows NT writes are allocating
// in L3 (evicting input) rather than streaming -- a slow allocate path.
// m13 copy sustains ~3.15 TB/s write-side, so 1.6 is our path, not HBM.
//
// This round: R6 byte-for-byte, with NT stores -> plain cached stores
// (global_store_dwordx4 through L2 write-back; full 64B lines, wave-wide
// 1 KB contiguous). Single variable. Compute path untouched (bit-exact:
// decay=0.5 and o*VTH in {0,0.5} are exact products; absmax 0.0 in R6/R9).

#define VTH 0.5f
#define T_STEPS 100
#define W 64                  // neurons per block == threads per block (1 wave)
#define K 25                  // float4s per neuron row (100 floats)

typedef float vfloat4 __attribute__((ext_vector_type(4)));

__global__ __launch_bounds__(64) void lif_kernel(const float* __restrict__ x,
                                                 const float* __restrict__ decay_p,
                                                 float* __restrict__ out,
                                                 int n_neurons) {
    __shared__ vfloat4 lds4[W * K];   // 25,600 B flat mirror of this block's slab

    const int lane = threadIdx.x;
    const float decay = decay_p[0];
    const size_t base_f4 = (size_t)blockIdx.x * (W * K);

    const vfloat4* __restrict__ g4 = (const vfloat4*)x + base_f4;
    vfloat4* __restrict__ o4 = (vfloat4*)out + base_f4;

    // ---- Stage: 25 coalesced 1 KB wave-wide loads, all issued before any
    // LDS write, then ds_write_b128 into the flat slab layout.
    vfloat4 v[K];
    #pragma unroll
    for (int k = 0; k < K; ++k) v[k] = g4[k * W + lane];
    #pragma unroll
    for (int k = 0; k < K; ++k) lds4[k * W + lane] = v[k];

    // ---- Compute: lane owns neuron `lane`; row = float4s [lane*K, lane*K+K).
    // In-place overwrite x -> o. (Single wave: no barrier needed; compiler
    // orders ds ops via lgkmcnt.)
    float u = 0.0f, o = 0.0f;
    #pragma unroll
    for (int i = 0; i < K; ++i) {
        vfloat4 t = lds4[lane * K + i];
        u = decay * u + t.x - o * VTH; o = (u > VTH) ? 1.0f : 0.0f; t.x = o;
        u = decay * u + t.y - o * VTH; o = (u > VTH) ? 1.0f : 0.0f; t.y = o;
        u = decay * u + t.z - o * VTH; o = (u > VTH) ? 1.0f : 0.0f; t.z = o;
        u = decay * u + t.w - o * VTH; o = (u > VTH) ? 1.0f : 0.0f; t.w = o;
        lds4[lane * K + i] = t;
    }

    // ---- Store: lane-contiguous LDS reads (2-way max = free), line-perfect
    // 1 KB wave-wide CACHED stores (the A/B variable: was nontemporal).
    #pragma unroll
    for (int k = 0; k < K; ++k) {
        o4[k * W + lane] = lds4[k * W + lane];
    }
}

extern "C" void kernel_launch(void* const* d_in, const int* in_sizes, int n_in,
                              void* d_out, int out_size, void* d_ws, size_t ws_size,
                              hipStream_t stream) {
    const float* x = (const float*)d_in[0];
    const float* decay = (const float*)d_in[1];
    float* out = (float*)d_out;

    const int n_neurons = in_sizes[0] / T_STEPS;   // 262,144
    const int grid = n_neurons / W;                // 4096 single-wave blocks

    lif_kernel<<<grid, W, 0, stream>>>(x, decay, out, n_neurons);
}